// Round 1
// 404.008 us; speedup vs baseline: 1.0173x; 1.0173x over previous
//
#include <hip/hip_runtime.h>

typedef __bf16 bf16x8 __attribute__((ext_vector_type(8)));
typedef float f32x4 __attribute__((ext_vector_type(4)));

__device__ inline unsigned short f2bf(float f) {
    unsigned x = __builtin_bit_cast(unsigned, f);
    x += 0x7fffu + ((x >> 16) & 1u);   // RNE
    return (unsigned short)(x >> 16);
}
__device__ inline unsigned pack2bf(float lo, float hi) {
    return (unsigned)f2bf(lo) | ((unsigned)f2bf(hi) << 16);
}
__device__ inline void cvt8(uint4 u, float* o) {
    o[0] = __builtin_bit_cast(float, u.x << 16);
    o[1] = __builtin_bit_cast(float, u.x & 0xffff0000u);
    o[2] = __builtin_bit_cast(float, u.y << 16);
    o[3] = __builtin_bit_cast(float, u.y & 0xffff0000u);
    o[4] = __builtin_bit_cast(float, u.z << 16);
    o[5] = __builtin_bit_cast(float, u.z & 0xffff0000u);
    o[6] = __builtin_bit_cast(float, u.w << 16);
    o[7] = __builtin_bit_cast(float, u.w & 0xffff0000u);
}
// exact-erf GELU via Abramowitz-Stegun 7.1.26 (|err| <= 1.5e-7)
__device__ inline float gelu_f(float v) {
    float x = fabsf(v) * 0.70710678118654752f;
    float td = __builtin_amdgcn_rcpf(1.0f + 0.3275911f * x);
    float p = ((((1.061405429f * td - 1.453152027f) * td + 1.421413741f) * td
                - 0.284496736f) * td + 0.254829592f) * td;
    float e = __expf(-x * x);
    float er = 1.0f - p * e;
    float s = v < 0.0f ? -er : er;
    return 0.5f * v * (1.0f + s);
}

// ---------------------------------------------------------------------------
// Fused shift+GEMM (R6): swapped-operand MFMA + LDS-staged coalesced epilogue.
//  - mfma(W_frag, X_frag, acc): C/D col=lane&15 -> X-row(mr), row=4*kq+r ->
//    output channel. Each lane holds 4 CONSECUTIVE channels per nt.
//  - Epilogue: after all MFMAs + 1 barrier, reuse the W LDS region as a
//    per-wave staging buffer; write 8B/16B packed chunks, read back
//    row-linear, store 64-lane x 16B = 1KB fully-coalesced lines.
//    (R5's 80 scalar 2B stores/thread made 32B scatter chunks -> 2.5x
//    WRITE_SIZE amplification + RMW FETCH.)
//  - Both A-tiles prefetched before W-stage (more bytes in flight).
// ---------------------------------------------------------------------------
template <int AXIS, bool FP32IN>
__device__ inline void load_a_raw(const void* __restrict__ Xv, int row, uint4* u,
                                  float4* f, int kq) {
    const int n = row & 32767;
    const int coord = (AXIS == 0) ? (n >> 10) : (AXIS == 1) ? ((n >> 5) & 31) : (n & 31);
    const int stride = (AXIS == 0) ? 1024 : (AXIS == 1) ? 32 : 1;
#pragma unroll
    for (int g = 0; g < 5; g++) {
        int s = 2 - g;
        bool ok = (unsigned)(coord + s) < 32u;
        int srow = ok ? row + s * stride : row;
        size_t off = (size_t)srow * 160 + g * 32 + kq * 8;
        if (FP32IN) {
            const float* p = (const float*)Xv + off;
            float4 r0 = ((const float4*)p)[0];
            float4 r1 = ((const float4*)p)[1];
            if (!ok) { r0 = make_float4(0, 0, 0, 0); r1 = make_float4(0, 0, 0, 0); }
            f[g * 2] = r0; f[g * 2 + 1] = r1;
        } else {
            uint4 v = *(const uint4*)((const unsigned short*)Xv + off);
            if (!ok) v = make_uint4(0, 0, 0, 0);
            u[g] = v;
        }
    }
}

template <bool FP32IN>
__device__ inline void pack_a(const uint4* u, const float4* f, uint4* a) {
#pragma unroll
    for (int g = 0; g < 5; g++) {
        if (FP32IN) {
            float4 r0 = f[g * 2], r1 = f[g * 2 + 1];
            a[g] = make_uint4(pack2bf(r0.x, r0.y), pack2bf(r0.z, r0.w),
                              pack2bf(r1.x, r1.y), pack2bf(r1.z, r1.w));
        } else {
            a[g] = u[g];
        }
    }
}

// MFMAs only; operands SWAPPED vs R5 (W as A, X as B). acc[nt][r] =
// Y[xrow = base+mr][co = nt*16 + kq*4 + r].
__device__ inline void tile_compute(const unsigned short* __restrict__ lw,
                                    const uint4* a, f32x4* acc, int mr, int kq) {
#pragma unroll
    for (int g = 0; g < 5; g++) {
        bf16x8 xf = __builtin_bit_cast(bf16x8, a[g]);
        const unsigned short* bp = lw + mr * 168 + g * 32 + kq * 8;
#pragma unroll
        for (int nt = 0; nt < 10; nt++) {
            bf16x8 wf = __builtin_bit_cast(bf16x8, *(const uint4*)(bp + nt * 16 * 168));
            acc[nt] = __builtin_amdgcn_mfma_f32_16x16x32_bf16(wf, xf, acc[nt], 0, 0, 0);
        }
    }
}

// Bias(+GELU) -> stage wave's 16x160 tile in LDS slot -> coalesced stores.
// bf16: slot stride 168 shorts (5376B/slot, slots 0..7 fit in lw).
// fp32: slot stride 164 floats (10496B/slot, slots 0..3 fit in lw).
template <bool GELU, bool F32OUT>
__device__ inline void stage_store(unsigned short* __restrict__ lbase,
                                   const f32x4* acc, const float* __restrict__ Bs,
                                   void* __restrict__ Yv, int rowbase,
                                   int lane, int slot, int mr, int kq) {
    if (F32OUT) {
        float* sw = (float*)lbase + slot * (16 * 164);
#pragma unroll
        for (int nt = 0; nt < 10; nt++) {
            float4 bb = *(const float4*)(Bs + nt * 16 + kq * 4);
            float v0 = acc[nt][0] + bb.x, v1 = acc[nt][1] + bb.y,
                  v2 = acc[nt][2] + bb.z, v3 = acc[nt][3] + bb.w;
            if (GELU) { v0 = gelu_f(v0); v1 = gelu_f(v1); v2 = gelu_f(v2); v3 = gelu_f(v3); }
            *(float4*)(sw + mr * 164 + nt * 16 + kq * 4) = make_float4(v0, v1, v2, v3);
        }
#pragma unroll
        for (int p = 0; p < 10; p++) {
            int idx = p * 256 + lane * 4;
            int row = idx / 160;
            int col = idx - row * 160;
            float4 v = *(const float4*)(sw + row * 164 + col);
            *(float4*)((float*)Yv + (size_t)rowbase * 160 + idx) = v;
        }
    } else {
        unsigned short* sw = lbase + slot * (16 * 168);
#pragma unroll
        for (int nt = 0; nt < 10; nt++) {
            float4 bb = *(const float4*)(Bs + nt * 16 + kq * 4);
            float v0 = acc[nt][0] + bb.x, v1 = acc[nt][1] + bb.y,
                  v2 = acc[nt][2] + bb.z, v3 = acc[nt][3] + bb.w;
            if (GELU) { v0 = gelu_f(v0); v1 = gelu_f(v1); v2 = gelu_f(v2); v3 = gelu_f(v3); }
            uint2 pk;
            pk.x = pack2bf(v0, v1);
            pk.y = pack2bf(v2, v3);
            *(uint2*)(sw + mr * 168 + nt * 16 + kq * 4) = pk;
        }
#pragma unroll
        for (int p = 0; p < 5; p++) {
            int idx = p * 512 + lane * 8;
            int row = idx / 160;
            int col = idx - row * 160;
            uint4 v = *(const uint4*)(sw + row * 168 + col);
            *(uint4*)((unsigned short*)Yv + (size_t)rowbase * 160 + idx) = v;
        }
    }
}

template <int AXIS, bool GELU, bool FP32IN, bool F32OUT>
__global__ __launch_bounds__(256, 3) void gemm_shift(
    const void* __restrict__ Xv, const float* __restrict__ Wm,
    const float* __restrict__ Bs, void* __restrict__ Yv) {
    __shared__ unsigned short lw[160 * 168];  // W^T bf16: [co][ci], 53760 B
    const int t = threadIdx.x;
    const int lane = t & 63, wv = t >> 6, mr = lane & 15, kq = lane >> 4;
    const int rbase = blockIdx.x * 128;

    // prefetch BOTH A tiles before W staging (max bytes in flight)
    uint4 u0[5], u1[5];
    float4 f0[10], f1[10];
    load_a_raw<AXIS, FP32IN>(Xv, rbase + wv * 16 + mr, u0, f0, kq);
    load_a_raw<AXIS, FP32IN>(Xv, rbase + 64 + wv * 16 + mr, u1, f1, kq);

    // stage W^T once: thread t = co (t<160), loop ci. Coalesced fp32 reads.
    if (t < 160) {
        const float* wp = Wm + t;
        unsigned short* lp = lw + t * 168;
#pragma unroll 4
        for (int ci = 0; ci < 160; ci++) lp[ci] = f2bf(wp[ci * 160]);
    }
    __syncthreads();

    uint4 a[5];
    f32x4 acc0[10] = {};
    pack_a<FP32IN>(u0, f0, a);
    tile_compute(lw, a, acc0, mr, kq);
    f32x4 acc1[10] = {};
    pack_a<FP32IN>(u1, f1, a);
    tile_compute(lw, a, acc1, mr, kq);

    __syncthreads();  // all waves done reading W -> lw reusable as staging
    const int slot0 = F32OUT ? wv : wv;
    const int slot1 = F32OUT ? wv : wv + 4;  // bf16 fits 8 slots: no serialization
    stage_store<GELU, F32OUT>(lw, acc0, Bs, Yv, rbase + wv * 16, lane, slot0, mr, kq);
    stage_store<GELU, F32OUT>(lw, acc1, Bs, Yv, rbase + 64 + wv * 16, lane, slot1, mr, kq);
}

// ---------------------------------------------------------------------------
// Depthwise 3x3x3 SAME conv + bias (UNCHANGED — clean attribution; its true
// duration will surface in this round's top-5).
// ---------------------------------------------------------------------------
__global__ __launch_bounds__(256) void dwconv3(
    const unsigned short* __restrict__ X, const float* __restrict__ Kw,
    const float* __restrict__ Bs, unsigned short* __restrict__ Y) {
    __shared__ float wl[20 * 220];
    const int t = threadIdx.x;
    for (int e = t; e < 160 * 27; e += 256) {
        int c = e / 27, tap = e % 27;
        wl[(c >> 3) * 220 + tap * 8 + (c & 7)] = Kw[e];
    }
    __syncthreads();

    int idx = blockIdx.x * 256 + t;
    int cc = idx % 20;
    int r = idx / 20;
    int dq = r & 7;  r >>= 3;
    int w = r & 31;  r >>= 5;
    int h = r & 31;
    int b = r >> 5;
    int d0 = dq << 2;

    float acc[4][8];
    {
        float bv[8];
        *(float4*)&bv[0] = ((const float4*)(Bs + cc * 8))[0];
        *(float4*)&bv[4] = ((const float4*)(Bs + cc * 8))[1];
#pragma unroll
        for (int od = 0; od < 4; od++)
#pragma unroll
            for (int j = 0; j < 8; j++) acc[od][j] = bv[j];
    }
    const float* wbase = &wl[cc * 220];
#pragma unroll
    for (int dh = -1; dh <= 1; dh++) {
        int hh = h + dh;
        if ((unsigned)hh >= 32u) continue;
#pragma unroll
        for (int dwi = -1; dwi <= 1; dwi++) {
            int ww = w + dwi;
            if ((unsigned)ww >= 32u) continue;
            const unsigned short* base =
                X + (size_t)(b * 32768 + hh * 1024 + ww * 32) * 160 + cc * 8;
            int tap0 = (dh + 1) * 9 + (dwi + 1) * 3;
            float wv_[24];
#pragma unroll
            for (int q2 = 0; q2 < 6; q2++)
                ((float4*)wv_)[q2] = *(const float4*)(wbase + tap0 * 8 + q2 * 4);
            float vb[6][8];
#pragma unroll
            for (int dd = 0; dd < 6; dd++) {
                int d = d0 - 1 + dd;
                if ((unsigned)d >= 32u) {
#pragma unroll
                    for (int j = 0; j < 8; j++) vb[dd][j] = 0.0f;
                } else {
                    cvt8(*(const uint4*)(base + d * 160), vb[dd]);
                }
            }
#pragma unroll
            for (int od = 0; od < 4; od++)
#pragma unroll
                for (int dd = 0; dd < 3; dd++)
#pragma unroll
                    for (int j = 0; j < 8; j++)
                        acc[od][j] += vb[od + dd][j] * wv_[dd * 8 + j];
        }
    }
#pragma unroll
    for (int od = 0; od < 4; od++) {
        unsigned short tmp[8];
#pragma unroll
        for (int j = 0; j < 8; j++) tmp[j] = f2bf(acc[od][j]);
        *(uint4*)(Y + (size_t)(b * 32768 + h * 1024 + w * 32 + d0 + od) * 160 + cc * 8) =
            *(uint4*)tmp;
    }
}

// ---------------------------------------------------------------------------
// Pipeline: shiftH+GEMM1 -> dw1 -> shiftW+GEMM2 -> dw2 -> shiftD+GEMM3+GELU
// d_out = float* (reference output fp32). Intermediates bf16, ping-pong
// d_out's first half <-> x's (dead-after-GEMM1) buffer; harness restores
// d_in before every launch.
// ---------------------------------------------------------------------------
extern "C" void kernel_launch(void* const* d_in, const int* in_sizes, int n_in,
                              void* d_out, int out_size, void* d_ws, size_t ws_size,
                              hipStream_t stream) {
    const void*  x    = d_in[0];                    // fp32 (B,N,C)
    const float* w1   = (const float*)d_in[4];
    const float* b1   = (const float*)d_in[5];
    const float* dw1  = (const float*)d_in[6];
    const float* bdw1 = (const float*)d_in[7];
    const float* w2   = (const float*)d_in[8];
    const float* b2   = (const float*)d_in[9];
    const float* dw2  = (const float*)d_in[10];
    const float* bdw2 = (const float*)d_in[11];
    const float* w3   = (const float*)d_in[12];
    const float* b3   = (const float*)d_in[13];
    unsigned short* obuf = (unsigned short*)d_out;    // bf16 view (first half)
    unsigned short* xbuf = (unsigned short*)d_in[0];  // dead after GEMM1

    gemm_shift<0, false, true,  false><<<1024, 256, 0, stream>>>(x,    w1, b1, obuf);
    dwconv3<<<2560, 256, 0, stream>>>(obuf, dw1, bdw1, xbuf);
    gemm_shift<1, false, false, false><<<1024, 256, 0, stream>>>(xbuf, w2, b2, obuf);
    dwconv3<<<2560, 256, 0, stream>>>(obuf, dw2, bdw2, xbuf);
    gemm_shift<2, true,  false, true ><<<1024, 256, 0, stream>>>(xbuf, w3, b3, d_out);
}

// Round 3
// 339.634 us; speedup vs baseline: 1.2101x; 1.1895x over previous
//
#include <hip/hip_runtime.h>

typedef __bf16 bf16x8 __attribute__((ext_vector_type(8)));
typedef float f32x4 __attribute__((ext_vector_type(4)));

__device__ inline unsigned short f2bf(float f) {
    unsigned x = __builtin_bit_cast(unsigned, f);
    x += 0x7fffu + ((x >> 16) & 1u);   // RNE
    return (unsigned short)(x >> 16);
}
__device__ inline unsigned pack2bf(float lo, float hi) {
    return (unsigned)f2bf(lo) | ((unsigned)f2bf(hi) << 16);
}
__device__ inline void cvt8(uint4 u, float* o) {
    o[0] = __builtin_bit_cast(float, u.x << 16);
    o[1] = __builtin_bit_cast(float, u.x & 0xffff0000u);
    o[2] = __builtin_bit_cast(float, u.y << 16);
    o[3] = __builtin_bit_cast(float, u.y & 0xffff0000u);
    o[4] = __builtin_bit_cast(float, u.z << 16);
    o[5] = __builtin_bit_cast(float, u.z & 0xffff0000u);
    o[6] = __builtin_bit_cast(float, u.w << 16);
    o[7] = __builtin_bit_cast(float, u.w & 0xffff0000u);
}
// exact-erf GELU via Abramowitz-Stegun 7.1.26 (|err| <= 1.5e-7)
__device__ inline float gelu_f(float v) {
    float x = fabsf(v) * 0.70710678118654752f;
    float td = __builtin_amdgcn_rcpf(1.0f + 0.3275911f * x);
    float p = ((((1.061405429f * td - 1.453152027f) * td + 1.421413741f) * td
                - 0.284496736f) * td + 0.254829592f) * td;
    float e = __expf(-x * x);
    float er = 1.0f - p * e;
    float s = v < 0.0f ? -er : er;
    return 0.5f * v * (1.0f + s);
}

// async global->LDS, 16B per lane (emits global_load_lds_dwordx4)
__device__ inline void gload_lds16(const void* g, void* l) {
    typedef __attribute__((address_space(1))) const unsigned int gq;
    typedef __attribute__((address_space(3))) unsigned int sq;
    __builtin_amdgcn_global_load_lds((gq*)g, (sq*)l, 16, 0, 0);
}

// ---------------------------------------------------------------------------
// R7b (R7 minus the zero-length-array compile error):
//  - prep_w3 converts all three W (fp32 160x160) to bf16 W^T in the PADDED
//    [co][168] layout, once, into d_ws.
//  - gemm_shift stages W via async global_load_lds(16B) — no VGPR roundtrip,
//    no f2bf, no ds_writes; overlapped with the A-tile prefetch.
//  - tile_compute_both: one wf ds_read feeds BOTH tiles' MFMAs.
// ---------------------------------------------------------------------------
__global__ __launch_bounds__(256) void prep_w3(const float* __restrict__ W1,
                                               const float* __restrict__ W2,
                                               const float* __restrict__ W3,
                                               unsigned short* __restrict__ dst) {
    int e = blockIdx.x * 256 + threadIdx.x;  // 3*160*168 = 80640 total
    int m = e / 26880;
    int r = e - m * 26880;
    int co = r / 168, ci = r - co * 168;
    const float* W = (m == 0) ? W1 : (m == 1) ? W2 : W3;
    dst[e] = (ci < 160) ? f2bf(W[ci * 160 + co]) : (unsigned short)0;
}

template <int AXIS, bool FP32IN>
__device__ inline void load_a_raw(const void* __restrict__ Xv, int row, uint4* u,
                                  float4* f, int kq) {
    const int n = row & 32767;
    const int coord = (AXIS == 0) ? (n >> 10) : (AXIS == 1) ? ((n >> 5) & 31) : (n & 31);
    const int stride = (AXIS == 0) ? 1024 : (AXIS == 1) ? 32 : 1;
#pragma unroll
    for (int g = 0; g < 5; g++) {
        int s = 2 - g;
        bool ok = (unsigned)(coord + s) < 32u;
        int srow = ok ? row + s * stride : row;
        size_t off = (size_t)srow * 160 + g * 32 + kq * 8;
        if (FP32IN) {
            const float* p = (const float*)Xv + off;
            float4 r0 = ((const float4*)p)[0];
            float4 r1 = ((const float4*)p)[1];
            if (!ok) { r0 = make_float4(0, 0, 0, 0); r1 = make_float4(0, 0, 0, 0); }
            f[g * 2] = r0; f[g * 2 + 1] = r1;
        } else {
            uint4 v = *(const uint4*)((const unsigned short*)Xv + off);
            if (!ok) v = make_uint4(0, 0, 0, 0);
            u[g] = v;
        }
    }
}

template <bool FP32IN>
__device__ inline void pack_a(const uint4* u, const float4* f, uint4* a) {
#pragma unroll
    for (int g = 0; g < 5; g++) {
        if (FP32IN) {
            float4 r0 = f[g * 2], r1 = f[g * 2 + 1];
            a[g] = make_uint4(pack2bf(r0.x, r0.y), pack2bf(r0.z, r0.w),
                              pack2bf(r1.x, r1.y), pack2bf(r1.z, r1.w));
        } else {
            a[g] = u[g];
        }
    }
}

// Both tiles share each wf read. acc[nt][r] = Y[xrow][co = nt*16 + kq*4 + r].
__device__ inline void tile_compute_both(const unsigned short* __restrict__ lw,
                                         const uint4* a0, const uint4* a1,
                                         f32x4* acc0, f32x4* acc1, int mr, int kq) {
#pragma unroll
    for (int g = 0; g < 5; g++) {
        bf16x8 x0 = __builtin_bit_cast(bf16x8, a0[g]);
        bf16x8 x1 = __builtin_bit_cast(bf16x8, a1[g]);
        const unsigned short* bp = lw + mr * 168 + g * 32 + kq * 8;
#pragma unroll
        for (int nt = 0; nt < 10; nt++) {
            bf16x8 wf = __builtin_bit_cast(bf16x8, *(const uint4*)(bp + nt * 16 * 168));
            acc0[nt] = __builtin_amdgcn_mfma_f32_16x16x32_bf16(wf, x0, acc0[nt], 0, 0, 0);
            acc1[nt] = __builtin_amdgcn_mfma_f32_16x16x32_bf16(wf, x1, acc1[nt], 0, 0, 0);
        }
    }
}

// Bias(+GELU) -> stage wave's 16x160 tile in LDS slot -> coalesced stores.
template <bool GELU, bool F32OUT>
__device__ inline void stage_store(unsigned short* __restrict__ lbase,
                                   const f32x4* acc, const float* __restrict__ Bs,
                                   void* __restrict__ Yv, int rowbase,
                                   int lane, int slot, int mr, int kq) {
    if (F32OUT) {
        float* sw = (float*)lbase + slot * (16 * 164);
#pragma unroll
        for (int nt = 0; nt < 10; nt++) {
            float4 bb = *(const float4*)(Bs + nt * 16 + kq * 4);
            float v0 = acc[nt][0] + bb.x, v1 = acc[nt][1] + bb.y,
                  v2 = acc[nt][2] + bb.z, v3 = acc[nt][3] + bb.w;
            if (GELU) { v0 = gelu_f(v0); v1 = gelu_f(v1); v2 = gelu_f(v2); v3 = gelu_f(v3); }
            *(float4*)(sw + mr * 164 + nt * 16 + kq * 4) = make_float4(v0, v1, v2, v3);
        }
#pragma unroll
        for (int p = 0; p < 10; p++) {
            int idx = p * 256 + lane * 4;
            int row = idx / 160;
            int col = idx - row * 160;
            float4 v = *(const float4*)(sw + row * 164 + col);
            *(float4*)((float*)Yv + (size_t)rowbase * 160 + idx) = v;
        }
    } else {
        unsigned short* sw = lbase + slot * (16 * 168);
#pragma unroll
        for (int nt = 0; nt < 10; nt++) {
            float4 bb = *(const float4*)(Bs + nt * 16 + kq * 4);
            float v0 = acc[nt][0] + bb.x, v1 = acc[nt][1] + bb.y,
                  v2 = acc[nt][2] + bb.z, v3 = acc[nt][3] + bb.w;
            if (GELU) { v0 = gelu_f(v0); v1 = gelu_f(v1); v2 = gelu_f(v2); v3 = gelu_f(v3); }
            uint2 pk;
            pk.x = pack2bf(v0, v1);
            pk.y = pack2bf(v2, v3);
            *(uint2*)(sw + mr * 168 + nt * 16 + kq * 4) = pk;
        }
#pragma unroll
        for (int p = 0; p < 5; p++) {
            int idx = p * 512 + lane * 8;
            int row = idx / 160;
            int col = idx - row * 160;
            uint4 v = *(const uint4*)(sw + row * 168 + col);
            *(uint4*)((unsigned short*)Yv + (size_t)rowbase * 160 + idx) = v;
        }
    }
}

template <int AXIS, bool GELU, bool FP32IN, bool F32OUT>
__global__ __launch_bounds__(256, 3) void gemm_shift(
    const void* __restrict__ Xv, const unsigned short* __restrict__ Wt,
    const float* __restrict__ Bs, void* __restrict__ Yv) {
    __shared__ unsigned short lw[160 * 168];  // W^T bf16: [co][ci], 53760 B
    const int t = threadIdx.x;
    const int lane = t & 63, wv = t >> 6, mr = lane & 15, kq = lane >> 4;
    const int rbase = blockIdx.x * 128;

    // async W DMA first (starts earliest, no VGPR use): 3360 16B chunks
    for (int i = t; i < 3360; i += 256)
        gload_lds16((const char*)Wt + i * 16, (char*)lw + i * 16);

    // prefetch BOTH A tiles while the DMA flows
    uint4 u0[5], u1[5];
    float4 f0[10], f1[10];
    load_a_raw<AXIS, FP32IN>(Xv, rbase + wv * 16 + mr, u0, f0, kq);
    load_a_raw<AXIS, FP32IN>(Xv, rbase + 64 + wv * 16 + mr, u1, f1, kq);

    __syncthreads();  // drains vmcnt (W DMA) + our A loads

    uint4 a0[5], a1[5];
    pack_a<FP32IN>(u0, f0, a0);
    pack_a<FP32IN>(u1, f1, a1);
    f32x4 acc0[10] = {};
    f32x4 acc1[10] = {};
    tile_compute_both(lw, a0, a1, acc0, acc1, mr, kq);

    __syncthreads();  // all waves done reading W -> lw reusable as staging
    const int slot0 = wv;
    const int slot1 = F32OUT ? wv : wv + 4;  // bf16 fits 8 slots: no serialization
    stage_store<GELU, F32OUT>(lw, acc0, Bs, Yv, rbase + wv * 16, lane, slot0, mr, kq);
    stage_store<GELU, F32OUT>(lw, acc1, Bs, Yv, rbase + 64 + wv * 16, lane, slot1, mr, kq);
}

// ---------------------------------------------------------------------------
// Depthwise 3x3x3 SAME conv + bias (UNCHANGED — clean attribution).
// ---------------------------------------------------------------------------
__global__ __launch_bounds__(256) void dwconv3(
    const unsigned short* __restrict__ X, const float* __restrict__ Kw,
    const float* __restrict__ Bs, unsigned short* __restrict__ Y) {
    __shared__ float wl[20 * 220];
    const int t = threadIdx.x;
    for (int e = t; e < 160 * 27; e += 256) {
        int c = e / 27, tap = e % 27;
        wl[(c >> 3) * 220 + tap * 8 + (c & 7)] = Kw[e];
    }
    __syncthreads();

    int idx = blockIdx.x * 256 + t;
    int cc = idx % 20;
    int r = idx / 20;
    int dq = r & 7;  r >>= 3;
    int w = r & 31;  r >>= 5;
    int h = r & 31;
    int b = r >> 5;
    int d0 = dq << 2;

    float acc[4][8];
    {
        float bv[8];
        *(float4*)&bv[0] = ((const float4*)(Bs + cc * 8))[0];
        *(float4*)&bv[4] = ((const float4*)(Bs + cc * 8))[1];
#pragma unroll
        for (int od = 0; od < 4; od++)
#pragma unroll
            for (int j = 0; j < 8; j++) acc[od][j] = bv[j];
    }
    const float* wbase = &wl[cc * 220];
#pragma unroll
    for (int dh = -1; dh <= 1; dh++) {
        int hh = h + dh;
        if ((unsigned)hh >= 32u) continue;
#pragma unroll
        for (int dwi = -1; dwi <= 1; dwi++) {
            int ww = w + dwi;
            if ((unsigned)ww >= 32u) continue;
            const unsigned short* base =
                X + (size_t)(b * 32768 + hh * 1024 + ww * 32) * 160 + cc * 8;
            int tap0 = (dh + 1) * 9 + (dwi + 1) * 3;
            float wv_[24];
#pragma unroll
            for (int q2 = 0; q2 < 6; q2++)
                ((float4*)wv_)[q2] = *(const float4*)(wbase + tap0 * 8 + q2 * 4);
            float vb[6][8];
#pragma unroll
            for (int dd = 0; dd < 6; dd++) {
                int d = d0 - 1 + dd;
                if ((unsigned)d >= 32u) {
#pragma unroll
                    for (int j = 0; j < 8; j++) vb[dd][j] = 0.0f;
                } else {
                    cvt8(*(const uint4*)(base + d * 160), vb[dd]);
                }
            }
#pragma unroll
            for (int od = 0; od < 4; od++)
#pragma unroll
                for (int dd = 0; dd < 3; dd++)
#pragma unroll
                    for (int j = 0; j < 8; j++)
                        acc[od][j] += vb[od + dd][j] * wv_[dd * 8 + j];
        }
    }
#pragma unroll
    for (int od = 0; od < 4; od++) {
        unsigned short tmp[8];
#pragma unroll
        for (int j = 0; j < 8; j++) tmp[j] = f2bf(acc[od][j]);
        *(uint4*)(Y + (size_t)(b * 32768 + h * 1024 + w * 32 + d0 + od) * 160 + cc * 8) =
            *(uint4*)tmp;
    }
}

// ---------------------------------------------------------------------------
// Pipeline: prep_w3 -> shiftH+GEMM1 -> dw1 -> shiftW+GEMM2 -> dw2 ->
//           shiftD+GEMM3+GELU
// ---------------------------------------------------------------------------
extern "C" void kernel_launch(void* const* d_in, const int* in_sizes, int n_in,
                              void* d_out, int out_size, void* d_ws, size_t ws_size,
                              hipStream_t stream) {
    const void*  x    = d_in[0];                    // fp32 (B,N,C)
    const float* w1   = (const float*)d_in[4];
    const float* b1   = (const float*)d_in[5];
    const float* dw1  = (const float*)d_in[6];
    const float* bdw1 = (const float*)d_in[7];
    const float* w2   = (const float*)d_in[8];
    const float* b2   = (const float*)d_in[9];
    const float* dw2  = (const float*)d_in[10];
    const float* bdw2 = (const float*)d_in[11];
    const float* w3   = (const float*)d_in[12];
    const float* b3   = (const float*)d_in[13];
    unsigned short* obuf = (unsigned short*)d_out;    // bf16 view (first half)
    unsigned short* xbuf = (unsigned short*)d_in[0];  // dead after GEMM1
    unsigned short* wbf  = (unsigned short*)d_ws;     // 3 x 26880 bf16 W^T padded

    prep_w3<<<315, 256, 0, stream>>>(w1, w2, w3, wbf);
    gemm_shift<0, false, true,  false><<<1024, 256, 0, stream>>>(x,    wbf,             b1, obuf);
    dwconv3<<<2560, 256, 0, stream>>>(obuf, dw1, bdw1, xbuf);
    gemm_shift<1, false, false, false><<<1024, 256, 0, stream>>>(xbuf, wbf + 26880,     b2, obuf);
    dwconv3<<<2560, 256, 0, stream>>>(obuf, dw2, bdw2, xbuf);
    gemm_shift<2, true,  false, true ><<<1024, 256, 0, stream>>>(xbuf, wbf + 2 * 26880, b3, d_out);
}

// Round 4
// 310.909 us; speedup vs baseline: 1.3219x; 1.0924x over previous
//
#include <hip/hip_runtime.h>

typedef __bf16 bf16x8 __attribute__((ext_vector_type(8)));
typedef float f32x4 __attribute__((ext_vector_type(4)));

__device__ inline unsigned short f2bf(float f) {
    unsigned x = __builtin_bit_cast(unsigned, f);
    x += 0x7fffu + ((x >> 16) & 1u);   // RNE
    return (unsigned short)(x >> 16);
}
__device__ inline unsigned pack2bf(float lo, float hi) {
    return (unsigned)f2bf(lo) | ((unsigned)f2bf(hi) << 16);
}
__device__ inline void cvt8(uint4 u, float* o) {
    o[0] = __builtin_bit_cast(float, u.x << 16);
    o[1] = __builtin_bit_cast(float, u.x & 0xffff0000u);
    o[2] = __builtin_bit_cast(float, u.y << 16);
    o[3] = __builtin_bit_cast(float, u.y & 0xffff0000u);
    o[4] = __builtin_bit_cast(float, u.z << 16);
    o[5] = __builtin_bit_cast(float, u.z & 0xffff0000u);
    o[6] = __builtin_bit_cast(float, u.w << 16);
    o[7] = __builtin_bit_cast(float, u.w & 0xffff0000u);
}
// exact-erf GELU via Abramowitz-Stegun 7.1.26 (|err| <= 1.5e-7)
__device__ inline float gelu_f(float v) {
    float x = fabsf(v) * 0.70710678118654752f;
    float td = __builtin_amdgcn_rcpf(1.0f + 0.3275911f * x);
    float p = ((((1.061405429f * td - 1.453152027f) * td + 1.421413741f) * td
                - 0.284496736f) * td + 0.254829592f) * td;
    float e = __expf(-x * x);
    float er = 1.0f - p * e;
    float s = v < 0.0f ? -er : er;
    return 0.5f * v * (1.0f + s);
}

// async global->LDS, 16B per lane (emits global_load_lds_dwordx4)
__device__ inline void gload_lds16(const void* g, void* l) {
    typedef __attribute__((address_space(1))) const unsigned int gq;
    typedef __attribute__((address_space(3))) unsigned int sq;
    __builtin_amdgcn_global_load_lds((gq*)g, (sq*)l, 16, 0, 0);
}

// ---------------------------------------------------------------------------
// prep_w3: all three W (fp32 160x160) -> bf16 W^T, PADDED [co][168], in d_ws.
// ---------------------------------------------------------------------------
__global__ __launch_bounds__(256) void prep_w3(const float* __restrict__ W1,
                                               const float* __restrict__ W2,
                                               const float* __restrict__ W3,
                                               unsigned short* __restrict__ dst) {
    int e = blockIdx.x * 256 + threadIdx.x;  // 3*160*168 = 80640 total
    int m = e / 26880;
    int r = e - m * 26880;
    int co = r / 168, ci = r - co * 168;
    const float* W = (m == 0) ? W1 : (m == 1) ? W2 : W3;
    dst[e] = (ci < 160) ? f2bf(W[ci * 160 + co]) : (unsigned short)0;
}

template <int AXIS, bool FP32IN>
__device__ inline void load_a_raw(const void* __restrict__ Xv, int row, uint4* u,
                                  float4* f, int kq) {
    const int n = row & 32767;
    const int coord = (AXIS == 0) ? (n >> 10) : (AXIS == 1) ? ((n >> 5) & 31) : (n & 31);
    const int stride = (AXIS == 0) ? 1024 : (AXIS == 1) ? 32 : 1;
#pragma unroll
    for (int g = 0; g < 5; g++) {
        int s = 2 - g;
        bool ok = (unsigned)(coord + s) < 32u;
        int srow = ok ? row + s * stride : row;
        size_t off = (size_t)srow * 160 + g * 32 + kq * 8;
        if (FP32IN) {
            const float* p = (const float*)Xv + off;
            float4 r0 = ((const float4*)p)[0];
            float4 r1 = ((const float4*)p)[1];
            if (!ok) { r0 = make_float4(0, 0, 0, 0); r1 = make_float4(0, 0, 0, 0); }
            f[g * 2] = r0; f[g * 2 + 1] = r1;
        } else {
            uint4 v = *(const uint4*)((const unsigned short*)Xv + off);
            if (!ok) v = make_uint4(0, 0, 0, 0);
            u[g] = v;
        }
    }
}

template <bool FP32IN>
__device__ inline void pack_a(const uint4* u, const float4* f, uint4* a) {
#pragma unroll
    for (int g = 0; g < 5; g++) {
        if (FP32IN) {
            float4 r0 = f[g * 2], r1 = f[g * 2 + 1];
            a[g] = make_uint4(pack2bf(r0.x, r0.y), pack2bf(r0.z, r0.w),
                              pack2bf(r1.x, r1.y), pack2bf(r1.z, r1.w));
        } else {
            a[g] = u[g];
        }
    }
}

// Both tiles share each wf read. acc[nt][r] = Y[xrow][co = nt*16 + kq*4 + r].
__device__ inline void tile_compute_both(const unsigned short* __restrict__ lw,
                                         const uint4* a0, const uint4* a1,
                                         f32x4* acc0, f32x4* acc1, int mr, int kq) {
#pragma unroll
    for (int g = 0; g < 5; g++) {
        bf16x8 x0 = __builtin_bit_cast(bf16x8, a0[g]);
        bf16x8 x1 = __builtin_bit_cast(bf16x8, a1[g]);
        const unsigned short* bp = lw + mr * 168 + g * 32 + kq * 8;
#pragma unroll
        for (int nt = 0; nt < 10; nt++) {
            bf16x8 wf = __builtin_bit_cast(bf16x8, *(const uint4*)(bp + nt * 16 * 168));
            acc0[nt] = __builtin_amdgcn_mfma_f32_16x16x32_bf16(wf, x0, acc0[nt], 0, 0, 0);
            acc1[nt] = __builtin_amdgcn_mfma_f32_16x16x32_bf16(wf, x1, acc1[nt], 0, 0, 0);
        }
    }
}

// Bias(+GELU) -> stage wave's 16x160 tile in LDS slot -> coalesced stores.
template <bool GELU, bool F32OUT>
__device__ inline void stage_store(unsigned short* __restrict__ lbase,
                                   const f32x4* acc, const float* __restrict__ Bs,
                                   void* __restrict__ Yv, int rowbase,
                                   int lane, int slot, int mr, int kq) {
    if (F32OUT) {
        float* sw = (float*)lbase + slot * (16 * 164);
#pragma unroll
        for (int nt = 0; nt < 10; nt++) {
            float4 bb = *(const float4*)(Bs + nt * 16 + kq * 4);
            float v0 = acc[nt][0] + bb.x, v1 = acc[nt][1] + bb.y,
                  v2 = acc[nt][2] + bb.z, v3 = acc[nt][3] + bb.w;
            if (GELU) { v0 = gelu_f(v0); v1 = gelu_f(v1); v2 = gelu_f(v2); v3 = gelu_f(v3); }
            *(float4*)(sw + mr * 164 + nt * 16 + kq * 4) = make_float4(v0, v1, v2, v3);
        }
#pragma unroll
        for (int p = 0; p < 10; p++) {
            int idx = p * 256 + lane * 4;
            int row = idx / 160;
            int col = idx - row * 160;
            float4 v = *(const float4*)(sw + row * 164 + col);
            *(float4*)((float*)Yv + (size_t)rowbase * 160 + idx) = v;
        }
    } else {
        unsigned short* sw = lbase + slot * (16 * 168);
#pragma unroll
        for (int nt = 0; nt < 10; nt++) {
            float4 bb = *(const float4*)(Bs + nt * 16 + kq * 4);
            float v0 = acc[nt][0] + bb.x, v1 = acc[nt][1] + bb.y,
                  v2 = acc[nt][2] + bb.z, v3 = acc[nt][3] + bb.w;
            if (GELU) { v0 = gelu_f(v0); v1 = gelu_f(v1); v2 = gelu_f(v2); v3 = gelu_f(v3); }
            uint2 pk;
            pk.x = pack2bf(v0, v1);
            pk.y = pack2bf(v2, v3);
            *(uint2*)(sw + mr * 168 + nt * 16 + kq * 4) = pk;
        }
#pragma unroll
        for (int p = 0; p < 5; p++) {
            int idx = p * 512 + lane * 8;
            int row = idx / 160;
            int col = idx - row * 160;
            uint4 v = *(const uint4*)(sw + row * 168 + col);
            *(uint4*)((unsigned short*)Yv + (size_t)rowbase * 160 + idx) = v;
        }
    }
}

template <int AXIS, bool GELU, bool FP32IN, bool F32OUT>
__global__ __launch_bounds__(256, 3) void gemm_shift(
    const void* __restrict__ Xv, const unsigned short* __restrict__ Wt,
    const float* __restrict__ Bs, void* __restrict__ Yv) {
    __shared__ unsigned short lw[160 * 168];  // W^T bf16: [co][ci], 53760 B
    const int t = threadIdx.x;
    const int lane = t & 63, wv = t >> 6, mr = lane & 15, kq = lane >> 4;
    const int rbase = blockIdx.x * 128;

    // async W DMA first (starts earliest, no VGPR use): 3360 16B chunks
    for (int i = t; i < 3360; i += 256)
        gload_lds16((const char*)Wt + i * 16, (char*)lw + i * 16);

    // prefetch BOTH A tiles while the DMA flows
    uint4 u0[5], u1[5];
    float4 f0[10], f1[10];
    load_a_raw<AXIS, FP32IN>(Xv, rbase + wv * 16 + mr, u0, f0, kq);
    load_a_raw<AXIS, FP32IN>(Xv, rbase + 64 + wv * 16 + mr, u1, f1, kq);

    __syncthreads();  // drains vmcnt (W DMA) + our A loads

    uint4 a0[5], a1[5];
    pack_a<FP32IN>(u0, f0, a0);
    pack_a<FP32IN>(u1, f1, a1);
    f32x4 acc0[10] = {};
    f32x4 acc1[10] = {};
    tile_compute_both(lw, a0, a1, acc0, acc1, mr, kq);

    __syncthreads();  // all waves done reading W -> lw reusable as staging
    const int slot0 = wv;
    const int slot1 = F32OUT ? wv : wv + 4;  // bf16 fits 8 slots: no serialization
    stage_store<GELU, F32OUT>(lw, acc0, Bs, Yv, rbase + wv * 16, lane, slot0, mr, kq);
    stage_store<GELU, F32OUT>(lw, acc1, Bs, Yv, rbase + 64 + wv * 16, lane, slot1, mr, kq);
}

// ---------------------------------------------------------------------------
// Depthwise 3x3x3 SAME conv + bias.
// R8: bijective XCD chunk swizzle — each XCD owns 320 contiguous blocks
// (= 16 consecutive h-rows), so h±1 neighbor-column reads (the 3x HBM
// read amplification: FETCH 125MB vs 42 ideal) become per-XCD L2 hits.
// Also: raw uint4 tap loads hoisted before the cvt batch (ILP).
// ---------------------------------------------------------------------------
__global__ __launch_bounds__(256) void dwconv3(
    const unsigned short* __restrict__ X, const float* __restrict__ Kw,
    const float* __restrict__ Bs, unsigned short* __restrict__ Y) {
    __shared__ float wl[20 * 220];
    const int t = threadIdx.x;
    for (int e = t; e < 160 * 27; e += 256) {
        int c = e / 27, tap = e % 27;
        wl[(c >> 3) * 220 + tap * 8 + (c & 7)] = Kw[e];
    }
    __syncthreads();

    // bijective XCD swizzle: 2560 blocks = 8 XCDs x 320-block contiguous chunks
    int bid = blockIdx.x;
    int swz = (bid & 7) * 320 + (bid >> 3);
    int idx = swz * 256 + t;

    int cc = idx % 20;
    int r = idx / 20;
    int dq = r & 7;  r >>= 3;
    int w = r & 31;  r >>= 5;
    int h = r & 31;
    int b = r >> 5;
    int d0 = dq << 2;

    float acc[4][8];
    {
        float bv[8];
        *(float4*)&bv[0] = ((const float4*)(Bs + cc * 8))[0];
        *(float4*)&bv[4] = ((const float4*)(Bs + cc * 8))[1];
#pragma unroll
        for (int od = 0; od < 4; od++)
#pragma unroll
            for (int j = 0; j < 8; j++) acc[od][j] = bv[j];
    }
    const float* wbase = &wl[cc * 220];
#pragma unroll
    for (int dh = -1; dh <= 1; dh++) {
        int hh = h + dh;
        if ((unsigned)hh >= 32u) continue;
#pragma unroll
        for (int dwi = -1; dwi <= 1; dwi++) {
            int ww = w + dwi;
            if ((unsigned)ww >= 32u) continue;
            const unsigned short* base =
                X + (size_t)(b * 32768 + hh * 1024 + ww * 32) * 160 + cc * 8;
            int tap0 = (dh + 1) * 9 + (dwi + 1) * 3;
            float wv_[24];
#pragma unroll
            for (int q2 = 0; q2 < 6; q2++)
                ((float4*)wv_)[q2] = *(const float4*)(wbase + tap0 * 8 + q2 * 4);
            // hoist the 6 raw loads, then convert (independent issue)
            uint4 ub[6];
#pragma unroll
            for (int dd = 0; dd < 6; dd++) {
                int d = d0 - 1 + dd;
                ub[dd] = ((unsigned)d < 32u) ? *(const uint4*)(base + d * 160)
                                             : make_uint4(0, 0, 0, 0);
            }
            float vb[6][8];
#pragma unroll
            for (int dd = 0; dd < 6; dd++) cvt8(ub[dd], vb[dd]);
#pragma unroll
            for (int od = 0; od < 4; od++)
#pragma unroll
                for (int dd = 0; dd < 3; dd++)
#pragma unroll
                    for (int j = 0; j < 8; j++)
                        acc[od][j] += vb[od + dd][j] * wv_[dd * 8 + j];
        }
    }
#pragma unroll
    for (int od = 0; od < 4; od++) {
        unsigned short tmp[8];
#pragma unroll
        for (int j = 0; j < 8; j++) tmp[j] = f2bf(acc[od][j]);
        *(uint4*)(Y + (size_t)(b * 32768 + h * 1024 + w * 32 + d0 + od) * 160 + cc * 8) =
            *(uint4*)tmp;
    }
}

// ---------------------------------------------------------------------------
// Pipeline: prep_w3 -> shiftH+GEMM1 -> dw1 -> shiftW+GEMM2 -> dw2 ->
//           shiftD+GEMM3+GELU
// ---------------------------------------------------------------------------
extern "C" void kernel_launch(void* const* d_in, const int* in_sizes, int n_in,
                              void* d_out, int out_size, void* d_ws, size_t ws_size,
                              hipStream_t stream) {
    const void*  x    = d_in[0];                    // fp32 (B,N,C)
    const float* w1   = (const float*)d_in[4];
    const float* b1   = (const float*)d_in[5];
    const float* dw1  = (const float*)d_in[6];
    const float* bdw1 = (const float*)d_in[7];
    const float* w2   = (const float*)d_in[8];
    const float* b2   = (const float*)d_in[9];
    const float* dw2  = (const float*)d_in[10];
    const float* bdw2 = (const float*)d_in[11];
    const float* w3   = (const float*)d_in[12];
    const float* b3   = (const float*)d_in[13];
    unsigned short* obuf = (unsigned short*)d_out;    // bf16 view (first half)
    unsigned short* xbuf = (unsigned short*)d_in[0];  // dead after GEMM1
    unsigned short* wbf  = (unsigned short*)d_ws;     // 3 x 26880 bf16 W^T padded

    prep_w3<<<315, 256, 0, stream>>>(w1, w2, w3, wbf);
    gemm_shift<0, false, true,  false><<<1024, 256, 0, stream>>>(x,    wbf,             b1, obuf);
    dwconv3<<<2560, 256, 0, stream>>>(obuf, dw1, bdw1, xbuf);
    gemm_shift<1, false, false, false><<<1024, 256, 0, stream>>>(xbuf, wbf + 26880,     b2, obuf);
    dwconv3<<<2560, 256, 0, stream>>>(obuf, dw2, bdw2, xbuf);
    gemm_shift<2, true,  false, true ><<<1024, 256, 0, stream>>>(xbuf, wbf + 2 * 26880, b3, d_out);
}